// Round 2
// baseline (1393.415 us; speedup 1.0000x reference)
//
#include <hip/hip_runtime.h>
#include <hip/hip_bf16.h>

#define BATCH 8
#define CH 256
#define SPAT 16384
#define TP 64
#define XP 268      // X/Q LDS pitch (halfwords): frag reads 2-way bank (free)
#define PVP 76      // P/V LDS pitch: frag reads + writes 2-way (free)

typedef __attribute__((ext_vector_type(4))) float f32x4;
typedef __attribute__((ext_vector_type(8))) __bf16 bf16x8;
typedef __attribute__((ext_vector_type(4))) __bf16 bf16x4;

// workspace float offsets
#define WS_SCALE   0        // 256
#define WS_SHIFT   256      // 256
#define WS_ROWSUM  512      // 2048 (zeroed)
#define WS_BNSUM   2560     // 256  (zeroed)
#define WS_BNSS    2816     // 256  (zeroed)
#define WS_POOLED  3072     // 16
#define WS_CTX     4096     // 262144 (zeroed)
#define WS_MBF     266240   // 8*256*256 bf16 = 131072 floats
#define WS_WKBF    397312   // 65536 bf16 = 32768 floats
#define WS_WQBF    430080
#define WS_WVBF    462848
// total 495616 floats = 1.89 MB

// per-tile qexp region: f = px*134 + c/2  (halfwords 2f,2f+1 = (px, c), (px, c+1))
// stored at out float offset ((b*256 + (f>>6))*16384 + s0 + (f&63)); 134 chunks/tile.

__device__ __forceinline__ void blockReduce2(float& a, float& b, volatile float* sm) {
    int lane = threadIdx.x & 63, w = threadIdx.x >> 6;
#pragma unroll
    for (int o = 32; o; o >>= 1) { a += __shfl_down(a, o); b += __shfl_down(b, o); }
    if (lane == 0) { sm[w] = a; sm[4 + w] = b; }
    __syncthreads();
    if (threadIdx.x == 0) {
        a = sm[0] + sm[1] + sm[2] + sm[3];
        b = sm[4] + sm[5] + sm[6] + sm[7];
    }
}

__global__ void ea_prep(const float* wk, const float* wq, const float* wv,
                        __bf16* wkb, __bf16* wqb, __bf16* wvb) {
    int i = blockIdx.x * 256 + threadIdx.x;
    wkb[i] = (__bf16)wk[i];
    wqb[i] = (__bf16)wq[i];
    wvb[i] = (__bf16)wv[i];
}

// ---- BN partial sums: 1024 blocks = (c, quarter) ----
__global__ void ea_bnpart(const float* x, float* sumbuf, float* ssbuf) {
    __shared__ float sm[8];
    int c = blockIdx.x & 255, part = blockIdx.x >> 8;
    float sum = 0.f, ss = 0.f;
    for (int b = part * 2; b < part * 2 + 2; b++) {
        const float4* p = (const float4*)(x + (size_t)(b * CH + c) * SPAT);
        for (int i = threadIdx.x; i < SPAT / 4; i += 256) {
            float4 v = p[i];
            sum += v.x + v.y + v.z + v.w;
            ss  += v.x * v.x + v.y * v.y + v.z * v.z + v.w * v.w;
        }
    }
    blockReduce2(sum, ss, sm);
    if (threadIdx.x == 0) { atomicAdd(sumbuf + c, sum); atomicAdd(ssbuf + c, ss); }
}

__global__ void ea_bnfin(const float* sumbuf, const float* ssbuf,
                         const float* gamma, const float* beta,
                         float* scale, float* shift) {
    int c = threadIdx.x;
    const float inv = 1.f / (float)(BATCH * SPAT);
    float mean = sumbuf[c] * inv;
    float var  = ssbuf[c] * inv - mean * mean;
    float rs   = rsqrtf(var + 1e-5f);
    float sc   = gamma[c] * rs;
    scale[c] = sc;
    shift[c] = beta[c] - mean * sc;
}

// per-wave 32x64 strip GEMM, K=256. A global bf16 (row stride 256), B = X LDS [px][ch] pitch XP.
__device__ __forceinline__ void mm2x4(const __bf16* __restrict__ A, const __bf16* Xl,
                                      int quad, int l15, f32x4 (&acc)[2][4]) {
#pragma unroll
    for (int ks = 0; ks < 8; ks++) {
        const int k0 = ks * 32 + quad * 8;
        bf16x8 a[2];
#pragma unroll
        for (int mt = 0; mt < 2; mt++)
            a[mt] = *(const bf16x8*)(A + (mt * 16 + l15) * 256 + k0);
#pragma unroll
        for (int nt = 0; nt < 4; nt++) {
            const __bf16* p = Xl + (nt * 16 + l15) * XP + k0;
            bf16x4 lo = *(const bf16x4*)p;
            bf16x4 hi = *(const bf16x4*)(p + 4);
            bf16x8 bb = __builtin_shufflevector(lo, hi, 0, 1, 2, 3, 4, 5, 6, 7);
#pragma unroll
            for (int mt = 0; mt < 2; mt++)
                acc[mt][nt] = __builtin_amdgcn_mfma_f32_16x16x32_bf16(a[mt], bb, acc[mt][nt], 0, 0, 0);
        }
    }
}

__device__ __forceinline__ unsigned int bfpack2(float a, float b) {
    union { __bf16 h[2]; unsigned int u; } p;
    p.h[0] = (__bf16)a; p.h[1] = (__bf16)b;
    return p.u;
}

// ---- fused: normalize + q/k/v projection (one head's 128 rows) + ctx accumulation ----
// grid 512 = b(8) x h(2) x g(32); each block: 8 tiles of 64 px.
__global__ __launch_bounds__(256, 3) void ea_projctx(
        const float* x, const float* scale, const float* shift,
        const __bf16* wkb, const __bf16* wqb, const __bf16* wvb,
        const float* bk, const float* bq, const float* bv,
        float* qout, float* rowsum, float* ctx) {
    __shared__ __bf16 XV[TP * XP];        // X (17152 hw); V (128*76=9728 hw) overlays after X dead
    __shared__ __bf16 P[128 * PVP];       // 9728 hw
    int bi = blockIdx.x;
    int b = bi >> 6, h = (bi >> 5) & 1, g = bi & 31;
    int t = threadIdx.x, lane = t & 63, w = t >> 6, quad = lane >> 4, l15 = lane & 15;
    int hb = h * 128, WB = w * 32;
    const __bf16* wkh = wkb + (size_t)(hb + WB) * 256;
    const __bf16* wqh = wqb + (size_t)(hb + WB) * 256;
    const __bf16* wvh = wvb + (size_t)(hb + WB) * 256;
    const f32x4 z = {0.f, 0.f, 0.f, 0.f};

    f32x4 cacc[2][8];
#pragma unroll
    for (int mt = 0; mt < 2; mt++)
#pragma unroll
        for (int nt = 0; nt < 8; nt++) cacc[mt][nt] = z;
    float rs[8];
#pragma unroll
    for (int j = 0; j < 8; j++) rs[j] = 0.f;

    for (int it = 0; it < 8; it++) {
        const int ts = g * 8 + it, s0 = ts * 64;
        // ---- stage normalized x tile ----
        {
            int px = t & 63, crow = t >> 6;
            const float* xb = x + (size_t)b * CH * SPAT + s0 + px;
#pragma unroll 8
            for (int i = 0; i < 64; i++) {
                int c = crow * 64 + i;
                float v = xb[(size_t)c * SPAT];
                XV[px * XP + c] = (__bf16)(v * scale[c] + shift[c]);
            }
        }
        __syncthreads();

        // ---- q projection -> exp -> qexp region of out ----
        {
            f32x4 acc[2][4];
#pragma unroll
            for (int mt = 0; mt < 2; mt++)
#pragma unroll
                for (int nt = 0; nt < 4; nt++) acc[mt][nt] = z;
            mm2x4(wqh, XV, quad, l15, acc);
#pragma unroll
            for (int mt = 0; mt < 2; mt++) {
                int c0 = hb + WB + mt * 16 + quad * 4;
                float4 bq4 = *(const float4*)(bq + c0);
#pragma unroll
                for (int nt = 0; nt < 4; nt++) {
                    int px = nt * 16 + l15;
                    float e0 = __expf(acc[mt][nt][0] + bq4.x);
                    float e1 = __expf(acc[mt][nt][1] + bq4.y);
                    float e2 = __expf(acc[mt][nt][2] + bq4.z);
                    float e3 = __expf(acc[mt][nt][3] + bq4.w);
                    int f = px * 134 + (c0 >> 1);
                    unsigned int lo = bfpack2(e0, e1), hi = bfpack2(e2, e3);
                    uint2* dst = (uint2*)(qout + ((size_t)((b << 8) + (f >> 6)) << 14) + s0 + (f & 63));
                    *dst = make_uint2(lo, hi);
                }
            }
        }
        // ---- k projection -> p=exp -> P LDS + rowsum partials ----
        {
            f32x4 acc[2][4];
#pragma unroll
            for (int mt = 0; mt < 2; mt++)
#pragma unroll
                for (int nt = 0; nt < 4; nt++) acc[mt][nt] = z;
            mm2x4(wkh, XV, quad, l15, acc);
#pragma unroll
            for (int mt = 0; mt < 2; mt++) {
                int r0 = WB + mt * 16 + quad * 4;   // local row in head
                float4 bk4 = *(const float4*)(bk + hb + r0);
#pragma unroll
                for (int nt = 0; nt < 4; nt++) {
                    int px = nt * 16 + l15;
                    float p0 = __expf(acc[mt][nt][0] + bk4.x);
                    float p1 = __expf(acc[mt][nt][1] + bk4.y);
                    float p2 = __expf(acc[mt][nt][2] + bk4.z);
                    float p3 = __expf(acc[mt][nt][3] + bk4.w);
                    rs[mt * 4 + 0] += p0; rs[mt * 4 + 1] += p1;
                    rs[mt * 4 + 2] += p2; rs[mt * 4 + 3] += p3;
                    P[(r0 + 0) * PVP + px] = (__bf16)p0;
                    P[(r0 + 1) * PVP + px] = (__bf16)p1;
                    P[(r0 + 2) * PVP + px] = (__bf16)p2;
                    P[(r0 + 3) * PVP + px] = (__bf16)p3;
                }
            }
        }
        // ---- v projection (regs) -> barrier -> V overlays X ----
        {
            f32x4 acc[2][4];
#pragma unroll
            for (int mt = 0; mt < 2; mt++)
#pragma unroll
                for (int nt = 0; nt < 4; nt++) acc[mt][nt] = z;
            mm2x4(wvh, XV, quad, l15, acc);
            __syncthreads();   // all waves done reading X
#pragma unroll
            for (int mt = 0; mt < 2; mt++) {
                int r0 = WB + mt * 16 + quad * 4;
                float4 bv4 = *(const float4*)(bv + hb + r0);
#pragma unroll
                for (int nt = 0; nt < 4; nt++) {
                    int px = nt * 16 + l15;
                    XV[(r0 + 0) * PVP + px] = (__bf16)(acc[mt][nt][0] + bv4.x);
                    XV[(r0 + 1) * PVP + px] = (__bf16)(acc[mt][nt][1] + bv4.y);
                    XV[(r0 + 2) * PVP + px] = (__bf16)(acc[mt][nt][2] + bv4.z);
                    XV[(r0 + 3) * PVP + px] = (__bf16)(acc[mt][nt][3] + bv4.w);
                }
            }
        }
        __syncthreads();
        // ---- ctx += P(32 rows strip) @ V^T, K=64 px ----
#pragma unroll
        for (int ks = 0; ks < 2; ks++) {
            const int px0 = ks * 32 + quad * 8;
            bf16x8 a2[2];
#pragma unroll
            for (int mt = 0; mt < 2; mt++) {
                const __bf16* p = P + (WB + mt * 16 + l15) * PVP + px0;
                bf16x4 lo = *(const bf16x4*)p;
                bf16x4 hi = *(const bf16x4*)(p + 4);
                a2[mt] = __builtin_shufflevector(lo, hi, 0, 1, 2, 3, 4, 5, 6, 7);
            }
#pragma unroll
            for (int nt = 0; nt < 8; nt++) {
                const __bf16* p = XV + (nt * 16 + l15) * PVP + px0;
                bf16x4 lo = *(const bf16x4*)p;
                bf16x4 hi = *(const bf16x4*)(p + 4);
                bf16x8 bb = __builtin_shufflevector(lo, hi, 0, 1, 2, 3, 4, 5, 6, 7);
#pragma unroll
                for (int mt = 0; mt < 2; mt++)
                    cacc[mt][nt] = __builtin_amdgcn_mfma_f32_16x16x32_bf16(a2[mt], bb, cacc[mt][nt], 0, 0, 0);
            }
        }
        __syncthreads();   // before next stage overwrites XV/P
    }

    // ---- rowsum: reduce over l15 lanes, atomic ----
#pragma unroll
    for (int j = 0; j < 8; j++) {
        float v = rs[j];
#pragma unroll
        for (int o = 1; o < 16; o <<= 1) v += __shfl_xor(v, o);
        if (l15 == 0) {
            int row = hb + WB + (j >> 2) * 16 + quad * 4 + (j & 3);
            atomicAdd(rowsum + b * CH + row, v);
        }
    }
    // ---- ctx atomics ----
    float* cb = ctx + (size_t)(b * 2 + h) * 16384;
#pragma unroll
    for (int mt = 0; mt < 2; mt++)
#pragma unroll
        for (int nt = 0; nt < 8; nt++)
#pragma unroll
            for (int r = 0; r < 4; r++) {
                int kk = WB + mt * 16 + quad * 4 + r, vv = nt * 16 + l15;
                atomicAdd(cb + kk * 128 + vv, cacc[mt][nt][r]);
            }
}

// ---- normalize ctx rows by rowsum, compute pooled mean ----
__global__ void ea_normpool(float* ctx, const float* rowsum, float* pooled) {
    __shared__ float sm[8];
    int bi = blockIdx.x, b = bi >> 1, h = bi & 1;
    float* base = ctx + (size_t)bi * 16384;
    const float* rsp = rowsum + b * CH + h * 128;
    float sum = 0.f, dummy = 0.f;
    for (int i = threadIdx.x; i < 16384; i += 256) {
        float v = base[i] / rsp[i >> 7];
        base[i] = v;
        sum += v;
    }
    blockReduce2(sum, dummy, sm);
    if (threadIdx.x == 0) pooled[bi] = sum * (1.f / 16384.f);
}

// ---- SE gate + fold w_rep into per-batch M (bf16) ----
__global__ __launch_bounds__(256) void ea_M(const float* ctx, const float* pooled,
                                            const float* wfc1, const float* bfc1,
                                            const float* wfc2, const float* bfc2,
                                            const float* wse, const float* bse,
                                            const float* wrep, __bf16* Mbf) {
    __shared__ float L[128 * 128];
    int bi = blockIdx.x, b = bi >> 3, h = (bi >> 2) & 1, strip = bi & 3;
    float p0 = pooled[b * 2], p1 = pooled[b * 2 + 1];
    float z10 = fmaxf(0.f, wfc1[0] * p0 + wfc1[1] * p1 + bfc1[0]);
    float z11 = fmaxf(0.f, wfc1[2] * p0 + wfc1[3] * p1 + bfc1[1]);
    float z20 = wfc2[0] * z10 + wfc2[1] * z11 + bfc2[0];
    float z21 = wfc2[2] * z10 + wfc2[3] * z11 + bfc2[1];
    float g0 = 1.f / (1.f + __expf(-z20)), g1 = 1.f / (1.f + __expf(-z21));
    float a0 = wse[0] * g0, a1 = wse[1] * g1, bs = bse[0];
    const float* c0 = ctx + (size_t)b * 2 * 16384;
    const float* c1 = c0 + 16384;
    for (int i = threadIdx.x; i < 16384; i += 256) L[i] = a0 * c0[i] + a1 * c1[i] + bs;
    __syncthreads();
    int o = strip * 64 + (threadIdx.x & 63), kb = (threadIdx.x >> 6) * 32;
    const float4* wr = (const float4*)(wrep + (size_t)o * 256 + h * 128);
    for (int kk = kb; kk < kb + 32; kk++) {
        const float4* Lr = (const float4*)(L + kk * 128);
        float acc = 0.f;
#pragma unroll 8
        for (int j = 0; j < 32; j++) {
            float4 w4 = wr[j];
            float4 l4 = Lr[j];
            acc += w4.x * l4.x + w4.y * l4.y + w4.z * l4.z + w4.w * l4.w;
        }
        Mbf[(size_t)(b * 256 + o) * 256 + h * 128 + kk] = (__bf16)acc;
    }
}

// ---- final: load qexp tile, channel softmax, out = M @ qsoft + b_rep ----
__global__ __launch_bounds__(256, 3) void ea_final2(const float* qsrc, const __bf16* Mbf,
                                                    const float* brep, float* out) {
    __shared__ __bf16 Q[TP * XP];     // 17152 hw = 4288 float2, exact
    __shared__ float psum[256];
    __shared__ float rcp2[TP * 2];
    int bi = blockIdx.x, b = bi >> 8, s0 = (bi & 255) * 64, t = threadIdx.x;
    int lane = t & 63, w = t >> 6, quad = lane >> 4, l15 = lane & 15;

    // stage qexp region -> LDS (layout-preserving copy)
    for (int i = t; i < 4288; i += 256) {
        int f = i * 2;
        float2 v = *(const float2*)(qsrc + ((size_t)((b << 8) + (f >> 6)) << 14) + s0 + (f & 63));
        ((float2*)Q)[i] = v;
    }
    __syncthreads();
    // column sums per (px, head)
    {
        int px = t & 63, hh = (t >> 6) & 1, part = t >> 7;
        const __bf16* qr = Q + px * XP + hh * 128 + part * 64;
        float s = 0.f;
#pragma unroll
        for (int j = 0; j < 16; j++) {
            bf16x4 q4 = *(const bf16x4*)(qr + j * 4);
            s += (float)q4[0] + (float)q4[1] + (float)q4[2] + (float)q4[3];
        }
        psum[t] = s;
    }
    __syncthreads();
    if (t < 128) {
        float tot = psum[t] + psum[t + 128];
        rcp2[(t & 63) * 2 + (t >> 6)] = 1.f / tot;
    }
    __syncthreads();
    // normalize Q in place (b64 vectorized)
    {
        int px = t & 63, cb = (t >> 6) * 64;
        float rr = rcp2[px * 2 + (cb >> 7)];
        __bf16* qr = Q + px * XP + cb;
#pragma unroll
        for (int j = 0; j < 16; j++) {
            bf16x4 q4 = *(bf16x4*)(qr + j * 4);
            q4[0] = (__bf16)((float)q4[0] * rr);
            q4[1] = (__bf16)((float)q4[1] * rr);
            q4[2] = (__bf16)((float)q4[2] * rr);
            q4[3] = (__bf16)((float)q4[3] * rr);
            *(bf16x4*)(qr + j * 4) = q4;
        }
    }
    __syncthreads();
    // out = M @ qsoft + b_rep   (wave: 64 rows x 64 px)
    {
        const f32x4 z = {0.f, 0.f, 0.f, 0.f};
        f32x4 acc[4][4];
#pragma unroll
        for (int mt = 0; mt < 4; mt++)
#pragma unroll
            for (int nt = 0; nt < 4; nt++) acc[mt][nt] = z;
        const __bf16* A = Mbf + (size_t)b * 65536 + (size_t)(w * 64) * 256;
#pragma unroll
        for (int ks = 0; ks < 8; ks++) {
            const int k0 = ks * 32 + quad * 8;
            bf16x8 a[4];
#pragma unroll
            for (int mt = 0; mt < 4; mt++)
                a[mt] = *(const bf16x8*)(A + (mt * 16 + l15) * 256 + k0);
#pragma unroll
            for (int nt = 0; nt < 4; nt++) {
                const __bf16* p = Q + (nt * 16 + l15) * XP + k0;
                bf16x4 lo = *(const bf16x4*)p;
                bf16x4 hi = *(const bf16x4*)(p + 4);
                bf16x8 bb = __builtin_shufflevector(lo, hi, 0, 1, 2, 3, 4, 5, 6, 7);
#pragma unroll
                for (int mt = 0; mt < 4; mt++)
                    acc[mt][nt] = __builtin_amdgcn_mfma_f32_16x16x32_bf16(a[mt], bb, acc[mt][nt], 0, 0, 0);
            }
        }
#pragma unroll
        for (int mt = 0; mt < 4; mt++) {
            int row = w * 64 + mt * 16 + quad * 4;
            float4 br4 = *(const float4*)(brep + row);
#pragma unroll
            for (int nt = 0; nt < 4; nt++) {
                int px = nt * 16 + l15;
                float* ob = out + (size_t)(b * 256 + row) * 16384 + s0 + px;
                ob[0 * 16384] = acc[mt][nt][0] + br4.x;
                ob[1 * 16384] = acc[mt][nt][1] + br4.y;
                ob[2 * 16384] = acc[mt][nt][2] + br4.z;
                ob[3 * 16384] = acc[mt][nt][3] + br4.w;
            }
        }
    }
}

extern "C" void kernel_launch(void* const* d_in, const int* in_sizes, int n_in,
                              void* d_out, int out_size, void* d_ws, size_t ws_size,
                              hipStream_t stream) {
    (void)in_sizes; (void)n_in; (void)out_size; (void)ws_size;
    const float* x     = (const float*)d_in[0];
    const float* gamma = (const float*)d_in[1];
    const float* beta  = (const float*)d_in[2];
    const float* wk    = (const float*)d_in[3];
    const float* bk    = (const float*)d_in[4];
    const float* wq    = (const float*)d_in[5];
    const float* bq    = (const float*)d_in[6];
    const float* wv    = (const float*)d_in[7];
    const float* bv    = (const float*)d_in[8];
    const float* wfc1  = (const float*)d_in[9];
    const float* bfc1  = (const float*)d_in[10];
    const float* wfc2  = (const float*)d_in[11];
    const float* bfc2  = (const float*)d_in[12];
    const float* wse   = (const float*)d_in[13];
    const float* bse   = (const float*)d_in[14];
    const float* wrep  = (const float*)d_in[15];
    const float* brep  = (const float*)d_in[16];

    float* ws = (float*)d_ws;
    __bf16* wkb = (__bf16*)(ws + WS_WKBF);
    __bf16* wqb = (__bf16*)(ws + WS_WQBF);
    __bf16* wvb = (__bf16*)(ws + WS_WVBF);
    __bf16* Mbf = (__bf16*)(ws + WS_MBF);
    float* out = (float*)d_out;

    hipMemsetAsync((void*)(ws + WS_ROWSUM), 0,
                   (size_t)(WS_CTX + 262144 - WS_ROWSUM) * sizeof(float), stream);
    ea_prep<<<256, 256, 0, stream>>>(wk, wq, wv, wkb, wqb, wvb);
    ea_bnpart<<<1024, 256, 0, stream>>>(x, ws + WS_BNSUM, ws + WS_BNSS);
    ea_bnfin<<<1, 256, 0, stream>>>(ws + WS_BNSUM, ws + WS_BNSS, gamma, beta,
                                    ws + WS_SCALE, ws + WS_SHIFT);
    ea_projctx<<<512, 256, 0, stream>>>(x, ws + WS_SCALE, ws + WS_SHIFT,
                                        wkb, wqb, wvb, bk, bq, bv,
                                        out, ws + WS_ROWSUM, ws + WS_CTX);
    ea_normpool<<<16, 256, 0, stream>>>(ws + WS_CTX, ws + WS_ROWSUM, ws + WS_POOLED);
    ea_M<<<64, 256, 0, stream>>>(ws + WS_CTX, ws + WS_POOLED, wfc1, bfc1, wfc2, bfc2,
                                 wse, bse, wrep, Mbf);
    ea_final2<<<2048, 256, 0, stream>>>(out, Mbf, brep, out);
}